// Round 15
// baseline (1155.334 us; speedup 1.0000x reference)
//
#include <hip/hip_runtime.h>
#include <hip/hip_bf16.h>
#include <stdint.h>

typedef __bf16 bf16x8 __attribute__((ext_vector_type(8)));
typedef float  f32x4  __attribute__((ext_vector_type(4)));
typedef float  f32x16 __attribute__((ext_vector_type(16)));
typedef short  short8v __attribute__((ext_vector_type(8)));

// ---------------- async global->LDS (wave-uniform LDS base + lane*16) -------
__device__ __forceinline__ void gload16(const void* gp, void* lp) {
  __builtin_amdgcn_global_load_lds(
      reinterpret_cast<const __attribute__((address_space(1))) uint32_t*>(
          reinterpret_cast<uintptr_t>(gp)),
      reinterpret_cast<__attribute__((address_space(3))) uint32_t*>(
          (uintptr_t)(uint32_t)reinterpret_cast<uintptr_t>(lp)),
      16, 0, 0);
}

// ---------------- octahedral group tables, parallel (1 thread / entry) ------
__global__ void build_tables(int* __restrict__ shift, int* __restrict__ rot) {
  int tid = blockIdx.x * blockDim.x + threadIdx.x;
  if (tid >= 576 + 648) return;
  const int perms[6][3] = {{0,1,2},{0,2,1},{1,0,2},{1,2,0},{2,0,1},{2,1,0}};
  const int psign[6] = {1,-1,-1,1,1,-1};
  int mats[24][3][3];
  int nm = 0;
  for (int pi = 0; pi < 6; ++pi)
    for (int sb = 0; sb < 8; ++sb) {
      int s0 = (sb&4)?-1:1, s1 = (sb&2)?-1:1, s2 = (sb&1)?-1:1;
      if (psign[pi]*s0*s1*s2 != 1) continue;
      int sg[3] = {s0,s1,s2};
      for (int i = 0; i < 3; ++i)
        for (int j = 0; j < 3; ++j)
          mats[nm][i][j] = (j == perms[pi][i]) ? sg[i] : 0;
      ++nm;
    }
  if (tid < 576) {
    int g = tid / 24, h = tid % 24;
    int P[3][3];
    for (int i = 0; i < 3; ++i)
      for (int j = 0; j < 3; ++j) {
        int v = 0;
        for (int k = 0; k < 3; ++k) v += mats[g][k][i]*mats[h][k][j];
        P[i][j] = v;
      }
    int id = -1;
    for (int m = 0; m < 24 && id < 0; ++m) {
      bool eq = true;
      for (int i = 0; i < 3; ++i)
        for (int j = 0; j < 3; ++j) eq = eq && (mats[m][i][j] == P[i][j]);
      if (eq) id = m;
    }
    shift[tid] = id;
  } else {
    int r = tid - 576;
    int g = r / 27, vox = r % 27;
    int z = vox / 9, y = (vox / 3) % 3, x = vox % 3;
    int v[3] = {z-1, y-1, x-1}, s[3];
    for (int j = 0; j < 3; ++j) {
      int a = 0;
      for (int i = 0; i < 3; ++i) a += v[i]*mats[g][i][j];
      s[j] = a + 1;
    }
    rot[g*27 + vox] = (s[0]*3 + s[1])*3 + s[2];
  }
}

// ---------------- weight fold: cw[oc][s][icf] bf16 --------------------------
__global__ void prep_weights(const float* __restrict__ w, const float* __restrict__ rw,
                             const int* __restrict__ shift, const int* __restrict__ rot,
                             __hip_bfloat16* __restrict__ cw) {
  int idx = blockIdx.x*256 + threadIdx.x;
  if (idx >= 384*27*384) return;
  int icf = idx % 384;
  int s   = (idx / 384) % 27;
  int oc  = idx / (384*27);
  int i = icf / 24, h = icf - i*24;
  int o = oc  / 24, g = oc  - o*24;
  int gg = shift[g*24 + h];
  int ss = rot[g*27 + s];
  float v = rw[g]      * w[((o*16 + i)*24 + gg)*27 + ss]
          + rw[24 + g] * w[(((16 + o)*16 + i)*24 + gg)*27 + ss];
  cw[idx] = __float2bfloat16(v);
}

// ---------------- x (NCDHW fp32) -> padded NDHWC bf16 -----------------------
__global__ void fill_xpad(const float* __restrict__ x, __hip_bfloat16* __restrict__ xp) {
  __shared__ __hip_bfloat16 tile[32][72];
  int t = threadIdx.x;
  int r = blockIdx.x;       // b*1024 + z*32 + y
  int cg = blockIdx.y;      // channel group of 64
  int b = r >> 10, zy = r & 1023, z = zy >> 5, y = zy & 31;
  const float* src = x + (((size_t)(b*384 + cg*64)) << 15) + zy*32;
#pragma unroll
  for (int p = 0; p < 2; ++p) {
    int chr = p*32 + (t >> 3), part = t & 7;
    float4 v = *(const float4*)(src + (((size_t)chr) << 15) + part*4);
    tile[part*4+0][chr] = __float2bfloat16(v.x);
    tile[part*4+1][chr] = __float2bfloat16(v.y);
    tile[part*4+2][chr] = __float2bfloat16(v.z);
    tile[part*4+3][chr] = __float2bfloat16(v.w);
  }
  __syncthreads();
  int pos = t >> 3, pc = t & 7;
  size_t vox = ((size_t)(b*34 + z + 1)*34 + (y + 1))*34 + (pos + 1);
  short8v val = *(const short8v*)&tile[pos][pc*8];
  *(short8v*)((short*)xp + vox*384 + cg*64 + pc*8) = val;
}

// ---------------- implicit-GEMM conv: BM=128 x BN=192, BK=64, 4 waves -------
// R14 with MFMA shape swapped to 32x32x16 (halves MFMA instruction count
// 48->24/iter; pipe floor 603K->~525K cyc @ m119's 2495 TF; LDS fragment
// traffic unchanged at 20 ds_read_b128/iter). Wave tile 64x96 = 2x3 frags of
// 32x32; acc = f32x16[2][3] (96 VGPR, same). Read slot: (ks*2+lhi)^(lane&7)
// — conflict-free within every 8-lane group (consecutive rows -> 8 distinct
// slots), same mechanism as before. C/D layout per m74/m101:
// col=lane&31, row=(reg&3)+8*(reg>>2)+4*(lane>>5).
// Pinned ADRs: 2 blocks/CU + BK=64 (R12: 3 thrash L2), B-via-LDS (R5/R10),
// __syncthreads-only sync (R8 race), both-sides XOR swizzle, tn-fast chunks.
// MODE 0: h = leaky(conv+bias) -> bf16 padded buffer
// MODE 1: out = leaky(conv+bias+resid) -> fp32 d_out (NCDHW)
template <int MODE>
__global__ __launch_bounds__(256, 2) void gconv(
    const __hip_bfloat16* __restrict__ src,
    const __hip_bfloat16* __restrict__ cw,
    const float* __restrict__ bias,
    const float* __restrict__ resid,
    __hip_bfloat16* __restrict__ hout,
    float* __restrict__ out) {
  __shared__ __align__(16) char lds[81920];   // 2 bufs x (A 16K | B 24K)
  const int tid  = threadIdx.x;
  const int lane = tid & 63, wid = tid >> 6;
  const int col = lane & 31, lhi = lane >> 5, xr8 = lane & 7;
  const int wm = wid >> 1, wn = wid & 1;      // 2M x 2N wave grid
  // XCD chunked swizzle: 1024 = 8 x 128, tn-fastest (B panel L2-resident)
  const int bid = blockIdx.x;
  const int swz = (bid & 7) * 128 + (bid >> 3);
  const int tm = swz >> 1;
  const int tn = swz & 1;
  const int ocb = tn * 192;
  const int pbase = tm * 128;
  const int b  = pbase >> 15;
  const int zy = (pbase & 32767) >> 5;
  const int z = zy >> 5, y0 = zy & 31;        // y0 multiple of 4

  f32x16 acc[2][3] = {};

  // ---- stage geometry: per K-tile A=16KB (4 gload16), B=24KB (6 gload16) --
  // chunk c = p*256 + tid -> row = p*32 + (tid>>3), slot = tid&7
  // content pre-swizzled at global source: slot s holds part s ^ (row&7)
  const int sx = tid >> 3;                     // 0..31
  const int slot_sw = ((tid & 7) ^ ((tid >> 3) & 7)) * 16;
  const char* srcB = (const char*)src;
  const char* cwB  = (const char*)cw;
  int gA[4], gB[6];
#pragma unroll
  for (int p = 0; p < 4; ++p)
    gA[p] = (((b*34 + z)*34 + (y0 + p))*34 + sx) * 768 + slot_sw;
#pragma unroll
  for (int p = 0; p < 6; ++p)
    gB[p] = (ocb + p*32 + sx) * 20736 + slot_sw;       // 20736 = 27*384*2

  // ---- ds_read (swizzled) offsets: slot(ks) = (ks*2 + lhi) ^ (lane&7) -----
  int sK[4];
#pragma unroll
  for (int k = 0; k < 4; ++k) sK[k] = ((k*2 + lhi) ^ xr8) * 16;
  const int arowb = (wm*64 + col) * 128;               // A region base
  const int browb = 16384 + (wn*96 + col) * 128;       // B region base

  // prologue: stage K-tile 0 -> buf0
#pragma unroll
  for (int p = 0; p < 4; ++p) gload16(srcB + gA[p], lds + p*4096 + tid*16);
#pragma unroll
  for (int p = 0; p < 6; ++p) gload16(cwB + gB[p], lds + 16384 + p*4096 + tid*16);
  __syncthreads();

  // stage counters for next K-tile (tile 1: tap 0, ic 1)
  int sic = 1, skx = 0, sky = 0, skz = 0, sta = 0, stb = 0;

  for (int t = 0; t < 162; ++t) {
    const int cur = t & 1;
    const char* Ab = lds + cur * 40960;
    // ---- ks0/ks1 read burst (first MFMA depends only on these 10) ----
    bf16x8 a0[2], a1[2], b0[3], b1[3];
#pragma unroll
    for (int fm = 0; fm < 2; ++fm) {
      a0[fm] = *(const bf16x8*)(Ab + arowb + fm*4096 + sK[0]);
      a1[fm] = *(const bf16x8*)(Ab + arowb + fm*4096 + sK[1]);
    }
#pragma unroll
    for (int fn = 0; fn < 3; ++fn) {
      b0[fn] = *(const bf16x8*)(Ab + browb + fn*4096 + sK[0]);
      b1[fn] = *(const bf16x8*)(Ab + browb + fn*4096 + sK[1]);
    }
    // ---- staging issue (independent vmcnt path; full-iteration slack) ----
    if (t < 161) {
      char* D = lds + (cur ^ 1) * 40960;
      const int ta = sta + sic*128, tb = stb + sic*128;
#pragma unroll
      for (int p = 0; p < 4; ++p) gload16(srcB + gA[p] + ta, D + p*4096 + tid*16);
#pragma unroll
      for (int p = 0; p < 6; ++p) gload16(cwB + gB[p] + tb, D + 16384 + p*4096 + tid*16);
      if (++sic == 6) {
        sic = 0;
        if (++skx == 3) { skx = 0; if (++sky == 3) { sky = 0; ++skz; } }
        sta = (skz*1156 + sky*34 + skx) * 768;
        stb += 768;
      }
    }
    // ---- ks2/ks3 read burst (hides under MFMA(ks0/1)) ----
    bf16x8 a2[2], a3[2], b2[3], b3[3];
#pragma unroll
    for (int fm = 0; fm < 2; ++fm) {
      a2[fm] = *(const bf16x8*)(Ab + arowb + fm*4096 + sK[2]);
      a3[fm] = *(const bf16x8*)(Ab + arowb + fm*4096 + sK[3]);
    }
#pragma unroll
    for (int fn = 0; fn < 3; ++fn) {
      b2[fn] = *(const bf16x8*)(Ab + browb + fn*4096 + sK[2]);
      b3[fn] = *(const bf16x8*)(Ab + browb + fn*4096 + sK[3]);
    }
    // ---- MFMA clusters: 24 x 32x32x16 ----
    __builtin_amdgcn_s_setprio(1);
#pragma unroll
    for (int fm = 0; fm < 2; ++fm)
#pragma unroll
      for (int fn = 0; fn < 3; ++fn)
        acc[fm][fn] = __builtin_amdgcn_mfma_f32_32x32x16_bf16(
            a0[fm], b0[fn], acc[fm][fn], 0, 0, 0);
#pragma unroll
    for (int fm = 0; fm < 2; ++fm)
#pragma unroll
      for (int fn = 0; fn < 3; ++fn)
        acc[fm][fn] = __builtin_amdgcn_mfma_f32_32x32x16_bf16(
            a1[fm], b1[fn], acc[fm][fn], 0, 0, 0);
#pragma unroll
    for (int fm = 0; fm < 2; ++fm)
#pragma unroll
      for (int fn = 0; fn < 3; ++fn)
        acc[fm][fn] = __builtin_amdgcn_mfma_f32_32x32x16_bf16(
            a2[fm], b2[fn], acc[fm][fn], 0, 0, 0);
#pragma unroll
    for (int fm = 0; fm < 2; ++fm)
#pragma unroll
      for (int fn = 0; fn < 3; ++fn)
        acc[fm][fn] = __builtin_amdgcn_mfma_f32_32x32x16_bf16(
            a3[fm], b3[fn], acc[fm][fn], 0, 0, 0);
    __builtin_amdgcn_s_setprio(0);
    __syncthreads();
  }

  // ---- epilogue (C/D: col=lane&31, row=(reg&3)+8*(reg>>2)+4*lhi) ----
  float bias_n[3];
  int oc_n[3];
#pragma unroll
  for (int fn = 0; fn < 3; ++fn) {
    int oc = ocb + wn*96 + fn*32 + col;
    oc_n[fn] = oc;
    bias_n[fn] = bias[oc / 24];
  }
  if (MODE == 0) {
    const int voxb = ((b*34 + z + 1)*34 + (y0 + 1))*34 + 1;
#pragma unroll
    for (int fm = 0; fm < 2; ++fm) {
      const int vrow = voxb + (wm*2 + fm)*34;
#pragma unroll
      for (int g = 0; g < 4; ++g) {
#pragma unroll
        for (int e = 0; e < 4; ++e) {
          int xo = 8*g + 4*lhi + e;
          __hip_bfloat16* dst = hout + (size_t)(vrow + xo)*384;
#pragma unroll
          for (int fn = 0; fn < 3; ++fn) {
            float v = acc[fm][fn][4*g + e] + bias_n[fn];
            v = v >= 0.f ? v : 0.01f*v;
            dst[oc_n[fn]] = __float2bfloat16(v);
          }
        }
      }
    }
  } else {
    const int zyx0 = pbase & 32767;
#pragma unroll
    for (int fm = 0; fm < 2; ++fm) {
#pragma unroll
      for (int fn = 0; fn < 3; ++fn) {
        size_t ofs0 = (((size_t)(b*384 + oc_n[fn])) << 15) + zyx0
                    + wm*64 + fm*32 + 4*lhi;
#pragma unroll
        for (int g = 0; g < 4; ++g) {
          float4 res = *(const float4*)(resid + ofs0 + 8*g);
          float rv[4] = {res.x, res.y, res.z, res.w};
          float ov[4];
#pragma unroll
          for (int e = 0; e < 4; ++e) {
            float v = acc[fm][fn][4*g + e] + bias_n[fn] + rv[e];
            ov[e] = v >= 0.f ? v : 0.01f*v;
          }
          float4 o4 = make_float4(ov[0], ov[1], ov[2], ov[3]);
          *(float4*)(out + ofs0 + 8*g) = o4;
        }
      }
    }
  }
}

extern "C" void kernel_launch(void* const* d_in, const int* in_sizes, int n_in,
                              void* d_out, int out_size, void* d_ws, size_t ws_size,
                              hipStream_t stream) {
  const float* x   = (const float*)d_in[0];
  const float* w1  = (const float*)d_in[1];
  const float* rw1 = (const float*)d_in[2];
  const float* b1  = (const float*)d_in[3];
  const float* w2  = (const float*)d_in[4];
  const float* rw2 = (const float*)d_in[5];
  const float* b2  = (const float*)d_in[6];
  float* out = (float*)d_out;

  char* ws = (char*)d_ws;
  int* shiftT = (int*)ws;
  int* rotT   = (int*)(ws + 2304);
  const size_t CW_BYTES  = (size_t)384*27*384*2;
  const size_t PAD_BYTES = (size_t)2*34*34*34*384*2;
  __hip_bfloat16* cw1  = (__hip_bfloat16*)(ws + 8192);
  __hip_bfloat16* cw2  = (__hip_bfloat16*)(ws + 8192 + CW_BYTES);
  __hip_bfloat16* xpad = (__hip_bfloat16*)(ws + 8192 + 2*CW_BYTES);
  __hip_bfloat16* hpad = (__hip_bfloat16*)(ws + 8192 + 2*CW_BYTES + PAD_BYTES);

  hipMemsetAsync(xpad, 0, PAD_BYTES, stream);
  hipMemsetAsync(hpad, 0, PAD_BYTES, stream);
  build_tables<<<5, 256, 0, stream>>>(shiftT, rotT);
  prep_weights<<<(384*27*384 + 255)/256, 256, 0, stream>>>(w1, rw1, shiftT, rotT, cw1);
  prep_weights<<<(384*27*384 + 255)/256, 256, 0, stream>>>(w2, rw2, shiftT, rotT, cw2);
  fill_xpad<<<dim3(2048, 6), 256, 0, stream>>>(x, xpad);
  gconv<0><<<dim3(1024, 1), 256, 0, stream>>>(xpad, cw1, b1, nullptr, hpad, nullptr);
  gconv<1><<<dim3(1024, 1), 256, 0, stream>>>(hpad, cw2, b2, x, nullptr, out);
}

// Round 16
// 959.928 us; speedup vs baseline: 1.2036x; 1.2036x over previous
//
#include <hip/hip_runtime.h>
#include <hip/hip_bf16.h>
#include <stdint.h>

typedef __bf16 bf16x8 __attribute__((ext_vector_type(8)));
typedef float  f32x4  __attribute__((ext_vector_type(4)));
typedef short  short8v __attribute__((ext_vector_type(8)));

// ---------------- async global->LDS (wave-uniform LDS base + lane*16) -------
__device__ __forceinline__ void gload16(const void* gp, void* lp) {
  __builtin_amdgcn_global_load_lds(
      reinterpret_cast<const __attribute__((address_space(1))) uint32_t*>(
          reinterpret_cast<uintptr_t>(gp)),
      reinterpret_cast<__attribute__((address_space(3))) uint32_t*>(
          (uintptr_t)(uint32_t)reinterpret_cast<uintptr_t>(lp)),
      16, 0, 0);
}

// ---------------- octahedral group tables, parallel (1 thread / entry) ------
__global__ void build_tables(int* __restrict__ shift, int* __restrict__ rot) {
  int tid = blockIdx.x * blockDim.x + threadIdx.x;
  if (tid >= 576 + 648) return;
  const int perms[6][3] = {{0,1,2},{0,2,1},{1,0,2},{1,2,0},{2,0,1},{2,1,0}};
  const int psign[6] = {1,-1,-1,1,1,-1};
  int mats[24][3][3];
  int nm = 0;
  for (int pi = 0; pi < 6; ++pi)
    for (int sb = 0; sb < 8; ++sb) {
      int s0 = (sb&4)?-1:1, s1 = (sb&2)?-1:1, s2 = (sb&1)?-1:1;
      if (psign[pi]*s0*s1*s2 != 1) continue;
      int sg[3] = {s0,s1,s2};
      for (int i = 0; i < 3; ++i)
        for (int j = 0; j < 3; ++j)
          mats[nm][i][j] = (j == perms[pi][i]) ? sg[i] : 0;
      ++nm;
    }
  if (tid < 576) {
    int g = tid / 24, h = tid % 24;
    int P[3][3];
    for (int i = 0; i < 3; ++i)
      for (int j = 0; j < 3; ++j) {
        int v = 0;
        for (int k = 0; k < 3; ++k) v += mats[g][k][i]*mats[h][k][j];
        P[i][j] = v;
      }
    int id = -1;
    for (int m = 0; m < 24 && id < 0; ++m) {
      bool eq = true;
      for (int i = 0; i < 3; ++i)
        for (int j = 0; j < 3; ++j) eq = eq && (mats[m][i][j] == P[i][j]);
      if (eq) id = m;
    }
    shift[tid] = id;
  } else {
    int r = tid - 576;
    int g = r / 27, vox = r % 27;
    int z = vox / 9, y = (vox / 3) % 3, x = vox % 3;
    int v[3] = {z-1, y-1, x-1}, s[3];
    for (int j = 0; j < 3; ++j) {
      int a = 0;
      for (int i = 0; i < 3; ++i) a += v[i]*mats[g][i][j];
      s[j] = a + 1;
    }
    rot[g*27 + vox] = (s[0]*3 + s[1])*3 + s[2];
  }
}

// ---------------- weight fold: cw[oc][s][icf] bf16 --------------------------
__global__ void prep_weights(const float* __restrict__ w, const float* __restrict__ rw,
                             const int* __restrict__ shift, const int* __restrict__ rot,
                             __hip_bfloat16* __restrict__ cw) {
  int idx = blockIdx.x*256 + threadIdx.x;
  if (idx >= 384*27*384) return;
  int icf = idx % 384;
  int s   = (idx / 384) % 27;
  int oc  = idx / (384*27);
  int i = icf / 24, h = icf - i*24;
  int o = oc  / 24, g = oc  - o*24;
  int gg = shift[g*24 + h];
  int ss = rot[g*27 + s];
  float v = rw[g]      * w[((o*16 + i)*24 + gg)*27 + ss]
          + rw[24 + g] * w[(((16 + o)*16 + i)*24 + gg)*27 + ss];
  cw[idx] = __float2bfloat16(v);
}

// ---------------- x (NCDHW fp32) -> padded NDHWC bf16 -----------------------
__global__ void fill_xpad(const float* __restrict__ x, __hip_bfloat16* __restrict__ xp) {
  __shared__ __hip_bfloat16 tile[32][72];
  int t = threadIdx.x;
  int r = blockIdx.x;       // b*1024 + z*32 + y
  int cg = blockIdx.y;      // channel group of 64
  int b = r >> 10, zy = r & 1023, z = zy >> 5, y = zy & 31;
  const float* src = x + (((size_t)(b*384 + cg*64)) << 15) + zy*32;
#pragma unroll
  for (int p = 0; p < 2; ++p) {
    int chr = p*32 + (t >> 3), part = t & 7;
    float4 v = *(const float4*)(src + (((size_t)chr) << 15) + part*4);
    tile[part*4+0][chr] = __float2bfloat16(v.x);
    tile[part*4+1][chr] = __float2bfloat16(v.y);
    tile[part*4+2][chr] = __float2bfloat16(v.z);
    tile[part*4+3][chr] = __float2bfloat16(v.w);
  }
  __syncthreads();
  int pos = t >> 3, pc = t & 7;
  size_t vox = ((size_t)(b*34 + z + 1)*34 + (y + 1))*34 + (pos + 1);
  short8v val = *(const short8v*)&tile[pos][pc*8];
  *(short8v*)((short*)xp + vox*384 + cg*64 + pc*8) = val;
}

// ---------------- implicit-GEMM conv: BM=128 x BN=192, BK=64, 4 waves -------
// R14 (best verified: 436us/gconv, MfmaUtil 61%, 0 conflicts). Half-split read
// pipelining: h0 fragments first, staging issue, h1 fragments, MFMA(h0/h1).
// Pinned ADRs: MFMA 16x16x32 with this read pattern (R15: 32x32 pattern =
// 5.3e7 bank conflicts, refuted); 2 blocks/CU + BK=64 (R12: 3 blocks thrash
// L2); B-via-LDS (R5/R10: reg-B refuted); __syncthreads-only sync (R8 race);
// both-sides XOR swizzle; tn-fastest XCD chunks (L2-resident B panel).
// MODE 0: h = leaky(conv+bias) -> bf16 padded buffer
// MODE 1: out = leaky(conv+bias+resid) -> fp32 d_out (NCDHW)
template <int MODE>
__global__ __launch_bounds__(256, 2) void gconv(
    const __hip_bfloat16* __restrict__ src,
    const __hip_bfloat16* __restrict__ cw,
    const float* __restrict__ bias,
    const float* __restrict__ resid,
    __hip_bfloat16* __restrict__ hout,
    float* __restrict__ out) {
  __shared__ __align__(16) char lds[81920];   // 2 bufs x (A 16K | B 24K)
  const int tid  = threadIdx.x;
  const int lane = tid & 63, wid = tid >> 6;
  const int lrow = lane & 15, lq = lane >> 4;
  const int wm = wid >> 1, wn = wid & 1;      // 2M x 2N wave grid
  // XCD chunked swizzle: 1024 = 8 x 128, tn-fastest (B panel L2-resident)
  const int bid = blockIdx.x;
  const int swz = (bid & 7) * 128 + (bid >> 3);
  const int tm = swz >> 1;
  const int tn = swz & 1;
  const int ocb = tn * 192;
  const int pbase = tm * 128;
  const int b  = pbase >> 15;
  const int zy = (pbase & 32767) >> 5;
  const int z = zy >> 5, y0 = zy & 31;        // y0 multiple of 4

  f32x4 acc[4][6] = {};

  // ---- stage geometry: per K-tile A=16KB (4 gload16), B=24KB (6 gload16) --
  // chunk c = p*256 + tid -> row = p*32 + (tid>>3), slot = tid&7
  // content pre-swizzled at global source: slot s holds part s ^ (row&7)
  const int sx = tid >> 3;                     // 0..31
  const int slot_sw = ((tid & 7) ^ ((tid >> 3) & 7)) * 16;
  const char* srcB = (const char*)src;
  const char* cwB  = (const char*)cw;
  int gA[4], gB[6];
#pragma unroll
  for (int p = 0; p < 4; ++p)
    gA[p] = (((b*34 + z)*34 + (y0 + p))*34 + sx) * 768 + slot_sw;
#pragma unroll
  for (int p = 0; p < 6; ++p)
    gB[p] = (ocb + p*32 + sx) * 20736 + slot_sw;       // 20736 = 27*384*2

  // ---- ds_read (swizzled) offsets ----
  const int xr = lrow & 7;
  const int s0 = (lq ^ xr) * 16;               // K half 0 (slots 0..3)
  const int s1 = ((4 | lq) ^ xr) * 16;         // K half 1 (slots 4..7)
  const int arow0 = (wm*64 + lrow) * 128;              // A region base
  const int brow0 = 16384 + (wn*96 + lrow) * 128;      // B region base

  // prologue: stage K-tile 0 -> buf0
#pragma unroll
  for (int p = 0; p < 4; ++p) gload16(srcB + gA[p], lds + p*4096 + tid*16);
#pragma unroll
  for (int p = 0; p < 6; ++p) gload16(cwB + gB[p], lds + 16384 + p*4096 + tid*16);
  __syncthreads();

  // stage counters for next K-tile (tile 1: tap 0, ic 1)
  int sic = 1, skx = 0, sky = 0, skz = 0, sta = 0, stb = 0;

  for (int t = 0; t < 162; ++t) {
    const int cur = t & 1;
    const char* Ab = lds + cur * 40960;
    // ---- K-half-0 read burst (first MFMA depends only on these 10) ----
    bf16x8 bfr0[6], af0[4];
#pragma unroll
    for (int ni = 0; ni < 6; ++ni)
      bfr0[ni] = *(const bf16x8*)(Ab + brow0 + ni*2048 + s0);
#pragma unroll
    for (int mi = 0; mi < 4; ++mi)
      af0[mi] = *(const bf16x8*)(Ab + arow0 + mi*2048 + s0);
    // ---- staging issue (independent vmcnt path; full-iteration slack) ----
    if (t < 161) {
      char* D = lds + (cur ^ 1) * 40960;
      const int ta = sta + sic*128, tb = stb + sic*128;
#pragma unroll
      for (int p = 0; p < 4; ++p) gload16(srcB + gA[p] + ta, D + p*4096 + tid*16);
#pragma unroll
      for (int p = 0; p < 6; ++p) gload16(cwB + gB[p] + tb, D + 16384 + p*4096 + tid*16);
      if (++sic == 6) {
        sic = 0;
        if (++skx == 3) { skx = 0; if (++sky == 3) { sky = 0; ++skz; } }
        sta = (skz*1156 + sky*34 + skx) * 768;
        stb += 768;
      }
    }
    // ---- K-half-1 read burst (hides under MFMA(h0)) ----
    bf16x8 bfr1[6], af1[4];
#pragma unroll
    for (int ni = 0; ni < 6; ++ni)
      bfr1[ni] = *(const bf16x8*)(Ab + brow0 + ni*2048 + s1);
#pragma unroll
    for (int mi = 0; mi < 4; ++mi)
      af1[mi] = *(const bf16x8*)(Ab + arow0 + mi*2048 + s1);
    // ---- MFMA clusters ----
    __builtin_amdgcn_s_setprio(1);
#pragma unroll
    for (int mi = 0; mi < 4; ++mi)
#pragma unroll
      for (int ni = 0; ni < 6; ++ni)
        acc[mi][ni] = __builtin_amdgcn_mfma_f32_16x16x32_bf16(
            af0[mi], bfr0[ni], acc[mi][ni], 0, 0, 0);
#pragma unroll
    for (int mi = 0; mi < 4; ++mi)
#pragma unroll
      for (int ni = 0; ni < 6; ++ni)
        acc[mi][ni] = __builtin_amdgcn_mfma_f32_16x16x32_bf16(
            af1[mi], bfr1[ni], acc[mi][ni], 0, 0, 0);
    __builtin_amdgcn_s_setprio(0);
    __syncthreads();
  }

  // ---- epilogue ----
  float bias_n[6];
  int oc_n[6];
#pragma unroll
  for (int ni = 0; ni < 6; ++ni) {
    int oc = ocb + wn*96 + ni*16 + lrow;
    oc_n[ni] = oc;
    bias_n[ni] = bias[oc / 24];
  }
  if (MODE == 0) {
    const int voxb = ((b*34 + z + 1)*34 + (y0 + 1))*34 + 1;
#pragma unroll
    for (int mi = 0; mi < 4; ++mi) {
#pragma unroll
      for (int e = 0; e < 4; ++e) {
        int rr = wm*64 + mi*16 + lq*4 + e;
        int vox = voxb + (rr >> 5)*34 + (rr & 31);
        __hip_bfloat16* dst = hout + (size_t)vox*384;
#pragma unroll
        for (int ni = 0; ni < 6; ++ni) {
          float v = acc[mi][ni][e] + bias_n[ni];
          v = v >= 0.f ? v : 0.01f*v;
          dst[oc_n[ni]] = __float2bfloat16(v);
        }
      }
    }
  } else {
    const int zyx0 = pbase & 32767;
#pragma unroll
    for (int mi = 0; mi < 4; ++mi) {
      int rrb = wm*64 + mi*16 + lq*4;
#pragma unroll
      for (int ni = 0; ni < 6; ++ni) {
        size_t ofs = (((size_t)(b*384 + oc_n[ni])) << 15) + zyx0 + rrb;
        float4 res = *(const float4*)(resid + ofs);
        float rv[4] = {res.x, res.y, res.z, res.w};
        float ov[4];
#pragma unroll
        for (int e = 0; e < 4; ++e) {
          float v = acc[mi][ni][e] + bias_n[ni] + rv[e];
          ov[e] = v >= 0.f ? v : 0.01f*v;
        }
        float4 o4 = make_float4(ov[0], ov[1], ov[2], ov[3]);
        *(float4*)(out + ofs) = o4;
      }
    }
  }
}

extern "C" void kernel_launch(void* const* d_in, const int* in_sizes, int n_in,
                              void* d_out, int out_size, void* d_ws, size_t ws_size,
                              hipStream_t stream) {
  const float* x   = (const float*)d_in[0];
  const float* w1  = (const float*)d_in[1];
  const float* rw1 = (const float*)d_in[2];
  const float* b1  = (const float*)d_in[3];
  const float* w2  = (const float*)d_in[4];
  const float* rw2 = (const float*)d_in[5];
  const float* b2  = (const float*)d_in[6];
  float* out = (float*)d_out;

  char* ws = (char*)d_ws;
  int* shiftT = (int*)ws;
  int* rotT   = (int*)(ws + 2304);
  const size_t CW_BYTES  = (size_t)384*27*384*2;
  const size_t PAD_BYTES = (size_t)2*34*34*34*384*2;
  __hip_bfloat16* cw1  = (__hip_bfloat16*)(ws + 8192);
  __hip_bfloat16* cw2  = (__hip_bfloat16*)(ws + 8192 + CW_BYTES);
  __hip_bfloat16* xpad = (__hip_bfloat16*)(ws + 8192 + 2*CW_BYTES);
  __hip_bfloat16* hpad = (__hip_bfloat16*)(ws + 8192 + 2*CW_BYTES + PAD_BYTES);

  hipMemsetAsync(xpad, 0, PAD_BYTES, stream);
  hipMemsetAsync(hpad, 0, PAD_BYTES, stream);
  build_tables<<<5, 256, 0, stream>>>(shiftT, rotT);
  prep_weights<<<(384*27*384 + 255)/256, 256, 0, stream>>>(w1, rw1, shiftT, rotT, cw1);
  prep_weights<<<(384*27*384 + 255)/256, 256, 0, stream>>>(w2, rw2, shiftT, rotT, cw2);
  fill_xpad<<<dim3(2048, 6), 256, 0, stream>>>(x, xpad);
  gconv<0><<<dim3(1024, 1), 256, 0, stream>>>(xpad, cw1, b1, nullptr, hpad, nullptr);
  gconv<1><<<dim3(1024, 1), 256, 0, stream>>>(hpad, cw2, b2, x, nullptr, out);
}